// Round 10
// baseline (1120.897 us; speedup 1.0000x reference)
//
#include <hip/hip_runtime.h>
#include <hip/hip_fp16.h>
#include <stdint.h>

typedef float f4 __attribute__((ext_vector_type(4)));

#define BSHIFT 8
#define BMASK  255
#define BCAP   8192   // edges per 256-node bucket (mean 4096 -> huge headroom)

// ---- device-scope grid barrier (all blocks co-resident by construction) ----
__device__ __forceinline__ void gridbar(int* bar, int target) {
    __threadfence();                 // release: flush this thread's writes device-wide
    __syncthreads();
    if (threadIdx.x == 0) {
        atomicAdd(bar, 1);
        while (atomicAdd(bar, 0) < target) __builtin_amdgcn_s_sleep(2);
    }
    __syncthreads();
    __threadfence();                 // acquire: invalidate stale cached lines
}

// ---- gemm phase: g16[row] = fp16(dinv[row] * (src[row] @ W)), 512-B row slots ----
// W fp32 in LDS (64 KB). 1024 thr: thread = (row r = t>>4, colgroup cg = t&15 -> 8 cols).
// In-place over src safe: a row's 16 threads are in ONE wave (lockstep: all k-loop
// reads complete before any lane's final store).
__device__ __forceinline__ void gemm_phase(f4* wlds, const float* __restrict__ src,
                                           const float* __restrict__ W,
                                           const float* __restrict__ dinv,
                                           __half* __restrict__ g16, int N, int NB) {
    int t = threadIdx.x;
    const f4* w4 = (const f4*)W;
    for (int i = t; i < 4096; i += 1024) wlds[i] = w4[i];
    __syncthreads();
    int r  = t >> 4;
    int cg = t & 15;
    int ntiles = (N + 63) >> 6;
    for (int tile = blockIdx.x; tile < ntiles; tile += NB) {
        int rw  = tile * 64 + r;
        int rwC = rw < N ? rw : N - 1;
        const f4* x4 = (const f4*)(src + (size_t)rwC * 128);
        float dv = dinv[rwC];
        f4 a0 = {0.f, 0.f, 0.f, 0.f}, a1 = {0.f, 0.f, 0.f, 0.f};
        for (int k4 = 0; k4 < 32; ++k4) {
            f4 xv = x4[k4];
#pragma unroll
            for (int kk = 0; kk < 4; ++kk) {
                float s = xv[kk];
                const f4* wr = &wlds[(k4 * 4 + kk) * 32 + 2 * cg];
                a0 += s * wr[0];
                a1 += s * wr[1];
            }
        }
        if (rw < N) {
            __half2 h0 = __floats2half2_rn(a0[0] * dv, a0[1] * dv);
            __half2 h1 = __floats2half2_rn(a0[2] * dv, a0[3] * dv);
            __half2 h2 = __floats2half2_rn(a1[0] * dv, a1[1] * dv);
            __half2 h3 = __floats2half2_rn(a1[2] * dv, a1[3] * dv);
            uint4 pk;
            pk.x = *(uint32_t*)&h0; pk.y = *(uint32_t*)&h1;
            pk.z = *(uint32_t*)&h2; pk.w = *(uint32_t*)&h3;
            *(uint4*)(g16 + (size_t)rw * 256 + cg * 8) = pk;
        }
    }
}

// ---- agg phase: one wave per node, lane owns cols {2L,2L+1}; fp32 accumulate ----
__device__ __forceinline__ void agg_phase(const __half2* __restrict__ gh,
                                          const int* __restrict__ csr,
                                          const int* __restrict__ off,
                                          const float* __restrict__ dinv,
                                          const float2* __restrict__ bias2,
                                          float2* __restrict__ out2, int N, int NB) {
    int t = threadIdx.x;
    int lane = t & 63;
    int gw = (blockIdx.x * 1024 + t) >> 6;
    int stride = NB * 16;
    for (int wid = gw; wid < N; wid += stride) {
        float di = dinv[wid];
        float2 self = __half22float2(gh[(size_t)wid * 128 + lane]);
        float a0 = self.x, a1 = self.y;
        int s = off[wid], e = off[wid + 1];
        for (int base = s; base < e; base += 64) {
            int idx = 0;
            if (base + lane < e) idx = csr[base + lane];
            int cnt = e - base; if (cnt > 64) cnt = 64;
            int tt = 0;
            for (; tt + 8 <= cnt; tt += 8) {
                float2 v[8];
#pragma unroll
                for (int u = 0; u < 8; ++u) {
                    int rr = __shfl(idx, tt + u);
                    v[u] = __half22float2(gh[(size_t)rr * 128 + lane]);
                }
#pragma unroll
                for (int u = 0; u < 8; ++u) { a0 += v[u].x; a1 += v[u].y; }
            }
            for (; tt < cnt; ++tt) {
                int rr = __shfl(idx, tt);
                float2 v = __half22float2(gh[(size_t)rr * 128 + lane]);
                a0 += v.x; a1 += v.y;
            }
        }
        float2 bb = bias2[lane];
        float2 o;
        o.x = fmaxf(fmaf(di, a0, bb.x), 0.0f);
        o.y = fmaxf(fmaf(di, a1, bb.y), 0.0f);
        out2[(size_t)wid * 64 + lane] = o;
    }
}

// ---- the persistent mega-kernel ----
__global__ __launch_bounds__(1024, 8) void mega(
    const int* __restrict__ row, const int* __restrict__ col,
    const float* __restrict__ W1, const float2* __restrict__ b1,
    const float* __restrict__ W2, const float2* __restrict__ b2,
    float* __restrict__ xbuf, float* __restrict__ out,
    int* __restrict__ off, float* __restrict__ dinv,
    int* __restrict__ csr, int* __restrict__ gcur,
    uint32_t* __restrict__ binned, int* __restrict__ bar,
    int N, int E, int nbuck, int NB)
{
    __shared__ f4 wlds[4096];   // 64 KB; aliased by bin/bucket scratch
    int t = threadIdx.x;
    __half* g16 = (__half*)xbuf;

    // ---- P1: bin edges into per-bucket regions, packed (row<<8 | node_in_bucket) ----
    {
        int* hist  = (int*)wlds;
        int* hbase = hist + 256;
        int chunks = (E + 4095) >> 12;
        for (int c = blockIdx.x; c < chunks; c += NB) {
            if (t < 256) hist[t] = 0;
            __syncthreads();
            int cc[4]; uint32_t pk[4];
            int e0 = (c << 12) + t;
#pragma unroll
            for (int i = 0; i < 4; ++i) {
                int e = e0 + (i << 10);
                cc[i] = -1; pk[i] = 0;
                if (e < E) {
                    int cv = col[e];
                    if ((unsigned)cv < (unsigned)N) {
                        cc[i] = cv >> BSHIFT;
                        pk[i] = ((uint32_t)row[e] << BSHIFT) | (uint32_t)(cv & BMASK);
                    }
                }
            }
#pragma unroll
            for (int i = 0; i < 4; ++i)
                if (cc[i] >= 0) atomicAdd(&hist[cc[i]], 1);
            __syncthreads();
            if (t < 256) {
                int hh = hist[t];
                if (hh > 0) hbase[t] = atomicAdd(&gcur[t], hh);
                hist[t] = 0;
            }
            __syncthreads();
#pragma unroll
            for (int i = 0; i < 4; ++i)
                if (cc[i] >= 0) {
                    int b = cc[i];
                    int p = hbase[b] + atomicAdd(&hist[b], 1);
                    if (p < BCAP) binned[((size_t)b << 13) + p] = pk[i];
                }
            __syncthreads();
        }
    }
    gridbar(bar, NB * 1);

    // ---- P2: per-bucket -> off / dinv / csr ----
    if (blockIdx.x < nbuck) {
        int b = blockIdx.x;
        int* wtot  = (int*)wlds;
        int* sbase = wtot + 4;
        int* hist  = sbase + 256;
        int* cur   = hist + 256;
        int lane = t & 63, w = t >> 6;
        int v = 0, inc = 0;
        if (t < 256) {
            v = (t < nbuck) ? gcur[t] : 0;
            inc = v;
#pragma unroll
            for (int d = 1; d < 64; d <<= 1) { int u = __shfl_up(inc, d); if (lane >= d) inc += u; }
            if (lane == 63) wtot[w] = inc;
        }
        __syncthreads();
        if (t < 256) {
            int wb = 0;
            for (int i = 0; i < w; ++i) wb += wtot[i];
            sbase[t] = wb + inc - v;
        }
        __syncthreads();
        int base_b = sbase[b];
        int c_b    = gcur[b];
        if (t < 256) hist[t] = 0;
        __syncthreads();
        const uint32_t* reg = binned + ((size_t)b << 13);
        for (int j = t; j < c_b; j += 1024) atomicAdd(&hist[reg[j] & BMASK], 1);
        __syncthreads();
        int h = 0, lo = 0;
        if (t < 256) {
            h = hist[t];
            int inc2 = h;
#pragma unroll
            for (int d = 1; d < 64; d <<= 1) { int u = __shfl_up(inc2, d); if (lane >= d) inc2 += u; }
            if (lane == 63) wtot[w] = inc2;
            lo = inc2 - h;
        }
        __syncthreads();
        if (t < 256) {
            int wb2 = 0;
            for (int i = 0; i < w; ++i) wb2 += wtot[i];
            lo += wb2;
            int node = (b << BSHIFT) + t;
            if (node < N) {
                off[node]  = base_b + lo;
                dinv[node] = rsqrtf((float)(h + 1));   // +1: self-loop
            }
            if (b == nbuck - 1 && t == 0) off[N] = sbase[nbuck - 1] + gcur[nbuck - 1];
            cur[t] = base_b + lo;
        }
        __syncthreads();
        for (int j = t; j < c_b; j += 1024) {
            uint32_t pv = reg[j];
            int p = atomicAdd(&cur[pv & BMASK], 1);
            csr[p] = (int)(pv >> BSHIFT);
        }
    }
    gridbar(bar, NB * 2);

    // ---- P3: layer-1 gemm (in-place xbuf -> fp16 slots) ----
    gemm_phase(wlds, xbuf, W1, dinv, g16, N, NB);
    gridbar(bar, NB * 3);

    // ---- P4: layer-1 aggregation -> act1 (fp32) in `out` ----
    agg_phase((const __half2*)g16, csr, off, dinv, b1, (float2*)out, N, NB);
    gridbar(bar, NB * 4);

    // ---- P5: layer-2 gemm (out -> fp16 slots over xbuf) ----
    gemm_phase(wlds, out, W2, dinv, g16, N, NB);
    gridbar(bar, NB * 5);

    // ---- P6: layer-2 aggregation -> final output ----
    agg_phase((const __half2*)g16, csr, off, dinv, b2, (float2*)out, N, NB);
}

// ---------- launch ----------
extern "C" void kernel_launch(void* const* d_in, const int* in_sizes, int n_in,
                              void* d_out, int out_size, void* d_ws, size_t ws_size,
                              hipStream_t stream) {
    float*       xbuf = (float*)d_in[0];        // fp32 input; reused as slotted fp16 g-table
    const int*   ei   = (const int*)d_in[1];
    const float* W1   = (const float*)d_in[2];
    const float* b1   = (const float*)d_in[3];
    const float* W2   = (const float*)d_in[4];
    const float* b2   = (const float*)d_in[5];
    float*       out  = (float*)d_out;

    int N = in_sizes[0] / 128;
    int E = in_sizes[1] / 2;
    const int* row = ei;          // sources (x_j)
    const int* col = ei + E;      // targets (aggregate index)

    int nbuck = (N + 255) >> BSHIFT;   // 196 for N=50000

    auto align256 = [](size_t v) { return (v + 255) & ~(size_t)255; };
    char* ws = (char*)d_ws;
    size_t pos = 0;
    int*      off    = (int*)(ws + pos);      pos += align256((size_t)(N + 1) * 4);
    float*    dinv   = (float*)(ws + pos);    pos += align256((size_t)N * 4);
    int*      csr    = (int*)(ws + pos);      pos += align256((size_t)E * 4);
    int*      gcur   = (int*)(ws + pos);      pos += align256(320 * 4);   // gcur[256] + bar
    int*      bar    = gcur + 256;
    uint32_t* binned = (uint32_t*)(ws + pos); pos += align256((size_t)nbuck * BCAP * 4);

    // exact co-residency grid (deadlock-safe): blocks/CU from the occupancy API
    int bpc = 0;
    (void)hipOccupancyMaxActiveBlocksPerMultiprocessor(&bpc, mega, 1024, 0);
    if (bpc < 1) bpc = 1;
    int NB = bpc * 256;            // 256 CUs on MI355X
    if (NB > 512) NB = 512;
    if (NB < nbuck) NB = nbuck;    // P2 needs one block per bucket (bpc>=1 => 256>=196)

    hipMemsetAsync(gcur, 0, 320 * 4, stream);   // zero bucket cursors + barrier counter
    mega<<<NB, 1024, 0, stream>>>(row, col, W1, (const float2*)b1, W2, (const float2*)b2,
                                  xbuf, out, off, dinv, csr, gcur, binned, bar,
                                  N, E, nbuck, NB);
}